// Round 4
// baseline (775.503 us; speedup 1.0000x reference)
//
#include <hip/hip_runtime.h>

// Problem constants (match reference)
#define DHW   (128*128*128)        // 2^21
#define CDHW  (4*DHW)              // 2^23
#define NTOT  (2*CDHW)             // 2^24 = 16,777,216
#define NSITE (2*DHW)              // B*DHW = 2^22 sites
#define NACC  1024                 // spread accumulator slots

// Fused-erosion tiling: output tile 16^3, halo 2 (two stencil steps)
#define TILE  16
#define IN_D  20                   // TILE + 4
#define S1_D  18                   // TILE + 2
#define IN_N  (IN_D*IN_D*IN_D)     // 8000
#define S1_N  (S1_D*S1_D*S1_D)     // 5832

// Kernel A: softmax over C=4, subtract one-hot(target), square -> buf0.
// Vectorized: each thread handles 4 consecutive sites. Also zero-inits accs.
__global__ __launch_bounds__(256) void softmax_sq_kernel(
    const float* __restrict__ in, const int* __restrict__ tgt,
    float* __restrict__ out, double* __restrict__ accs)
{
    int j4 = blockIdx.x * 256 + threadIdx.x;      // [0, NSITE/4)
    if (j4 < NACC) accs[j4] = 0.0;

    int base = j4 << 2;                           // site index [0, NSITE)
    int b = base >> 21;                           // DHW = 2^21
    int s = base & (DHW - 1);
    const float* p = in + (size_t)b * CDHW + s;

    float4 a0 = *(const float4*)(p);
    float4 a1 = *(const float4*)(p + DHW);
    float4 a2 = *(const float4*)(p + 2 * DHW);
    float4 a3 = *(const float4*)(p + 3 * DHW);
    int4   t  = *(const int4*)(tgt + base);

    float4 o0, o1, o2, o3;
    #define SOFTMAX1(K)                                                        \
    {                                                                          \
        float v0 = a0.K, v1 = a1.K, v2 = a2.K, v3 = a3.K;                      \
        float m  = fmaxf(fmaxf(v0, v1), fmaxf(v2, v3));                        \
        float e0 = expf(v0 - m), e1 = expf(v1 - m);                            \
        float e2 = expf(v2 - m), e3 = expf(v3 - m);                            \
        float inv = 1.0f / (e0 + e1 + e2 + e3);                                \
        int   tv = t.K;                                                        \
        float d0 = e0 * inv - (tv == 0 ? 1.0f : 0.0f);                         \
        float d1 = e1 * inv - (tv == 1 ? 1.0f : 0.0f);                         \
        float d2 = e2 * inv - (tv == 2 ? 1.0f : 0.0f);                         \
        float d3 = e3 * inv - (tv == 3 ? 1.0f : 0.0f);                         \
        o0.K = d0 * d0; o1.K = d1 * d1; o2.K = d2 * d2; o3.K = d3 * d3;        \
    }
    SOFTMAX1(x) SOFTMAX1(y) SOFTMAX1(z) SOFTMAX1(w)
    #undef SOFTMAX1

    float* q = out + (size_t)b * CDHW + s;
    *(float4*)(q)           = o0;
    *(float4*)(q + DHW)     = o1;
    *(float4*)(q + 2 * DHW) = o2;
    *(float4*)(q + 3 * DHW) = o3;
}

// Kernel B: TWO fused erosion steps via LDS tiling.
// Block owns a 16^3 tile of one (b,c) slab. Loads 20^3 (halo 2, zero-padded),
// computes step1 on 18^3 into LDS, step2 on 16^3. Accumulates
// coef1*step1 + coef2*step2 over owned points (f64), one atomic per block.
// store=0 skips the global write (last pass).
__global__ __launch_bounds__(256) void erode2_kernel(
    const float* __restrict__ src, float* __restrict__ dst,
    const float* __restrict__ kern, const float* __restrict__ bias,
    const float* __restrict__ weight, float coef1, float coef2,
    int store, double* __restrict__ accs)
{
    __shared__ float lin[IN_N];    // 32 KB
    __shared__ float ls1[S1_N];    // 23.3 KB

    int tid  = threadIdx.x;
    int tile = blockIdx.x & 511;                  // 8x8x8 tiles
    int bc   = blockIdx.x >> 9;                   // [0,8)
    int x0 = (tile & 7) << 4;
    int y0 = ((tile >> 3) & 7) << 4;
    int z0 = ((tile >> 6) & 7) << 4;

    const float* sp = src + ((size_t)bc << 21);
    float wk = kern[13];                          // all 7 taps equal
    float bs = bias[bc & 3];

    // ---- load 20^3 input region, zero-padded at volume edges ----
    for (int i = tid; i < IN_N; i += 256) {
        int lz = i / (IN_D * IN_D);
        int r  = i - lz * (IN_D * IN_D);
        int ly = r / IN_D;
        int lx = r - ly * IN_D;
        int gx = x0 + lx - 2, gy = y0 + ly - 2, gz = z0 + lz - 2;
        float v = 0.0f;
        if (((unsigned)gx < 128u) && ((unsigned)gy < 128u) && ((unsigned)gz < 128u))
            v = sp[(gz << 14) + (gy << 7) + gx];
        lin[i] = v;
    }
    __syncthreads();

    // ---- step 1 on 18^3 ----
    for (int i = tid; i < S1_N; i += 256) {
        int lz = i / (S1_D * S1_D);
        int r  = i - lz * (S1_D * S1_D);
        int ly = r / S1_D;
        int lx = r - ly * S1_D;
        int ci = (lz + 1) * (IN_D * IN_D) + (ly + 1) * IN_D + (lx + 1);
        float s = lin[ci] + lin[ci - 1] + lin[ci + 1]
                + lin[ci - IN_D] + lin[ci + IN_D]
                + lin[ci - IN_D * IN_D] + lin[ci + IN_D * IN_D];
        ls1[i] = fmaxf(s * wk + bs, 0.0f);
    }
    __syncthreads();

    // ---- step 2 on 16^3 + dual-step loss accumulation ----
    double part = 0.0;
    float* dp = dst + ((size_t)bc << 21);
    for (int i = tid; i < TILE * TILE * TILE; i += 256) {
        int lz = i >> 8;
        int ly = (i >> 4) & 15;
        int lx = i & 15;
        int ci = (lz + 1) * (S1_D * S1_D) + (ly + 1) * S1_D + (lx + 1);
        float c1 = ls1[ci];
        float s = c1 + ls1[ci - 1] + ls1[ci + 1]
                + ls1[ci - S1_D] + ls1[ci + S1_D]
                + ls1[ci - S1_D * S1_D] + ls1[ci + S1_D * S1_D];
        float v2 = fmaxf(s * wk + bs, 0.0f);
        part += (double)coef1 * (double)c1 + (double)coef2 * (double)v2;
        if (store)
            dp[((z0 + lz) << 14) + ((y0 + ly) << 7) + (x0 + lx)] = v2;
    }

    // ---- block reduction, one f64 atomic per block ----
    #pragma unroll
    for (int off = 32; off > 0; off >>= 1)
        part += __shfl_down(part, off, 64);

    __shared__ double wsum[4];
    int lane = tid & 63;
    int wid  = tid >> 6;
    if (lane == 0) wsum[wid] = part;
    __syncthreads();
    if (tid == 0) {
        double tot = wsum[0] + wsum[1] + wsum[2] + wsum[3];
        atomicAdd(&accs[blockIdx.x & (NACC - 1)], tot * (double)weight[bc]);
    }
}

// Reduce the NACC spread accumulators -> scalar mean.
__global__ __launch_bounds__(1024) void finalize_kernel(
    const double* __restrict__ accs, float* __restrict__ out)
{
    __shared__ double wsum[16];
    double v = accs[threadIdx.x];
    #pragma unroll
    for (int off = 32; off > 0; off >>= 1)
        v += __shfl_down(v, off, 64);
    int lane = threadIdx.x & 63;
    int wid  = threadIdx.x >> 6;
    if (lane == 0) wsum[wid] = v;
    __syncthreads();
    if (threadIdx.x == 0) {
        double tot = 0.0;
        #pragma unroll
        for (int i = 0; i < 16; ++i) tot += wsum[i];
        out[0] = (float)(tot / (double)NTOT);
    }
}

extern "C" void kernel_launch(void* const* d_in, const int* in_sizes, int n_in,
                              void* d_out, int out_size, void* d_ws, size_t ws_size,
                              hipStream_t stream) {
    const float* in     = (const float*)d_in[0];
    const int*   tgt    = (const int*)d_in[1];
    const float* weight = (const float*)d_in[2];
    const float* kern   = (const float*)d_in[3];
    const float* bias   = (const float*)d_in[4];
    float* out = (float*)d_out;

    char* ws = (char*)d_ws;
    float*  buf0 = (float*)ws;
    float*  buf1 = (float*)(ws + (size_t)NTOT * sizeof(float));
    double* accs = (double*)(ws + (size_t)NTOT * 2 * sizeof(float));

    // 1) softmax + one-hot + square (also zeroes accs)
    softmax_sq_kernel<<<(NSITE / 4) / 256, 256, 0, stream>>>(in, tgt, buf0, accs);

    // 2) 5 fused double-erosion passes; last pass skips the store
    float* cur = buf0;
    float* nxt = buf1;
    for (int p = 0; p < 5; ++p) {
        float c1 = (float)((2 * p + 1) * (2 * p + 1));
        float c2 = (float)((2 * p + 2) * (2 * p + 2));
        int   store = (p < 4) ? 1 : 0;
        erode2_kernel<<<512 * 8, 256, 0, stream>>>(
            cur, nxt, kern, bias, weight, c1, c2, store, accs);
        float* t = cur; cur = nxt; nxt = t;
    }

    // 3) reduce + mean
    finalize_kernel<<<1, 1024, 0, stream>>>(accs, out);
}

// Round 5
// 316.098 us; speedup vs baseline: 2.4534x; 2.4534x over previous
//
#include <hip/hip_runtime.h>

// Problem constants (match reference)
#define DHW   (128*128*128)        // 2^21
#define CDHW  (4*DHW)              // 2^23
#define NTOT  (2*CDHW)             // 2^24 = 16,777,216
#define NSITE (2*DHW)              // B*DHW = 2^22 sites
#define NACC  1024                 // spread accumulator slots

// z-marching fused-2 erosion tiling:
// owned tile 64(x) x 16(y) x 16(z); x-halo 4 (for float4 alignment), y-halo 2.
#define PITCH4   18                // float4 per row (72 floats)
#define IN_ROWS  20                // 16 + 2*2 y-halo
#define S1_ROWS  18                // 16 + 2*1
#define IN_P4    (IN_ROWS*PITCH4)  // 360 float4 per input plane
#define S1_P4    (S1_ROWS*PITCH4)  // 324 float4 per step1 plane
#define SLOT(z)  (((z) + 6) % 3)

// Kernel A: softmax over C=4, subtract one-hot(target), square -> buf0.
// Also zero-inits the spread accumulators.
__global__ __launch_bounds__(256) void softmax_sq_kernel(
    const float* __restrict__ in, const int* __restrict__ tgt,
    float* __restrict__ out, double* __restrict__ accs)
{
    int j4 = blockIdx.x * 256 + threadIdx.x;      // [0, NSITE/4)
    if (j4 < NACC) accs[j4] = 0.0;

    int base = j4 << 2;                           // site index [0, NSITE)
    int b = base >> 21;                           // DHW = 2^21
    int s = base & (DHW - 1);
    const float* p = in + (size_t)b * CDHW + s;

    float4 a0 = *(const float4*)(p);
    float4 a1 = *(const float4*)(p + DHW);
    float4 a2 = *(const float4*)(p + 2 * DHW);
    float4 a3 = *(const float4*)(p + 3 * DHW);
    int4   t  = *(const int4*)(tgt + base);

    float4 o0, o1, o2, o3;
    #define SOFTMAX1(K)                                                        \
    {                                                                          \
        float v0 = a0.K, v1 = a1.K, v2 = a2.K, v3 = a3.K;                      \
        float m  = fmaxf(fmaxf(v0, v1), fmaxf(v2, v3));                        \
        float e0 = expf(v0 - m), e1 = expf(v1 - m);                            \
        float e2 = expf(v2 - m), e3 = expf(v3 - m);                            \
        float inv = 1.0f / (e0 + e1 + e2 + e3);                                \
        int   tv = t.K;                                                        \
        float d0 = e0 * inv - (tv == 0 ? 1.0f : 0.0f);                         \
        float d1 = e1 * inv - (tv == 1 ? 1.0f : 0.0f);                         \
        float d2 = e2 * inv - (tv == 2 ? 1.0f : 0.0f);                         \
        float d3 = e3 * inv - (tv == 3 ? 1.0f : 0.0f);                         \
        o0.K = d0 * d0; o1.K = d1 * d1; o2.K = d2 * d2; o3.K = d3 * d3;        \
    }
    SOFTMAX1(x) SOFTMAX1(y) SOFTMAX1(z) SOFTMAX1(w)
    #undef SOFTMAX1

    float* q = out + (size_t)b * CDHW + s;
    *(float4*)(q)           = o0;
    *(float4*)(q + DHW)     = o1;
    *(float4*)(q + 2 * DHW) = o2;
    *(float4*)(q + 3 * DHW) = o3;
}

// Kernel B: TWO fused erosion steps, z-marching rolling planes.
// All LDS traffic is aligned float4 (b128) on consecutive lanes -> conflict-free.
__global__ __launch_bounds__(256, 4) void erode2_kernel(
    const float4* __restrict__ src, float4* __restrict__ dst,
    const float* __restrict__ kern, const float* __restrict__ bias,
    const float* __restrict__ weight, float c1, float c2,
    int store, double* __restrict__ accs)
{
    __shared__ float4 lin[3 * IN_P4];   // 17.3 KB
    __shared__ float4 ls1[3 * S1_P4];   // 15.6 KB
    __shared__ double wsum[4];

    int tid = threadIdx.x;
    int bid = blockIdx.x;
    int zb  = (bid & 7) << 4;                 // z-segment base
    int y0  = ((bid >> 3) & 7) << 4;
    int x0  = ((bid >> 6) & 1) << 6;
    int bc  = bid >> 7;                       // b*4 + c in [0,8)

    const float4* sp = src + ((size_t)bc << 19);   // slab = 2^21 floats = 2^19 f4
    float4*       dp = dst + ((size_t)bc << 19);
    float wk = kern[13];                      // all 7 taps equal
    float bs = bias[bc & 3];

    // ---- precomputed per-thread tables (all divs hoisted out of z-loop) ----
    // input load: 360 f4 over 256 threads -> 2 ragged iterations
    int  lgo[2], llo[2]; bool lval[2], lact[2];
    #pragma unroll
    for (int it = 0; it < 2; ++it) {
        int q = tid + it * 256;
        lact[it] = (q < IN_P4);
        if (!lact[it]) q = 0;
        int row = q / PITCH4;                 // [0,20)
        int col = q - row * PITCH4;           // [0,18)
        int gy  = y0 + row - 2;
        int gx4 = (x0 >> 2) + col - 1;        // float4 col in 32-wide volume row
        lval[it] = ((unsigned)gy < 128u) && ((unsigned)gx4 < 32u);
        lgo[it]  = gy * 32 + gx4;
        llo[it]  = q;
    }
    // step1 compute: 324 f4 groups over 256 threads -> 2 ragged iterations
    int sin_[2], sout_[2]; bool sact[2]; float4 smsk[2];
    #pragma unroll
    for (int it = 0; it < 2; ++it) {
        int g = tid + it * 256;
        sact[it] = (g < S1_P4);
        if (!sact[it]) g = 0;
        int r = g / PITCH4;                   // [0,18)
        int c = g - r * PITCH4;
        bool yok = ((unsigned)(y0 + r - 1) < 128u);
        int gx = x0 + 4 * c - 4;
        float4 m;
        m.x = (yok && (unsigned)(gx + 0) < 128u) ? 1.0f : 0.0f;
        m.y = (yok && (unsigned)(gx + 1) < 128u) ? 1.0f : 0.0f;
        m.z = (yok && (unsigned)(gx + 2) < 128u) ? 1.0f : 0.0f;
        m.w = (yok && (unsigned)(gx + 3) < 128u) ? 1.0f : 0.0f;
        smsk[it]  = m;
        sin_[it]  = (r + 1) * PITCH4 + c;     // center f4 idx in input plane
        sout_[it] = r * PITCH4 + c;           // f4 idx in s1 plane
    }
    // step2: one owned float4 per thread
    int txq = tid & 15;
    int ty  = tid >> 4;
    int cix = (ty + 1) * PITCH4 + 1 + txq;    // center f4 idx in s1 plane
    int go4 = (y0 + ty) * 32 + (x0 >> 2) + txq;

    // ---- phase lambdas ----
    auto load_plane = [&](int L) {
        bool zok = ((unsigned)L < 128u);
        const float4* zsp = zok ? (sp + (size_t)L * 4096) : sp;
        float4* lslot = lin + SLOT(L) * IN_P4;
        #pragma unroll
        for (int it = 0; it < 2; ++it) {
            if (lact[it]) {
                float4 v = make_float4(0.f, 0.f, 0.f, 0.f);
                if (zok && lval[it]) v = zsp[lgo[it]];
                lslot[llo[it]] = v;
            }
        }
    };
    auto s1_plane = [&](int zs) {
        bool zok = ((unsigned)zs < 128u);
        const float4* pzm = lin + SLOT(zs - 1) * IN_P4;
        const float4* pzc = lin + SLOT(zs)     * IN_P4;
        const float4* pzp = lin + SLOT(zs + 1) * IN_P4;
        float4* oslot = ls1 + SLOT(zs) * S1_P4;
        #pragma unroll
        for (int it = 0; it < 2; ++it) {
            if (sact[it]) {
                float4 v = make_float4(0.f, 0.f, 0.f, 0.f);
                if (zok) {
                    int ci = sin_[it];
                    float4 qC = pzc[ci];
                    float4 qL = pzc[ci - 1];          // only .w used (valid lanes)
                    float4 qR = pzc[ci + 1];          // only .x used
                    float4 qU = pzc[ci - PITCH4];
                    float4 qD = pzc[ci + PITCH4];
                    float4 qm = pzm[ci];
                    float4 qp = pzp[ci];
                    float4 m = smsk[it];
                    v.x = fmaxf((qC.x + qL.w + qC.y + qU.x + qD.x + qm.x + qp.x) * wk + bs, 0.f) * m.x;
                    v.y = fmaxf((qC.y + qC.x + qC.z + qU.y + qD.y + qm.y + qp.y) * wk + bs, 0.f) * m.y;
                    v.z = fmaxf((qC.z + qC.y + qC.w + qU.z + qD.z + qm.z + qp.z) * wk + bs, 0.f) * m.z;
                    v.w = fmaxf((qC.w + qC.z + qR.x + qU.w + qD.w + qm.w + qp.w) * wk + bs, 0.f) * m.w;
                }
                oslot[sout_[it]] = v;
            }
        }
    };

    // ---- pipeline prologue ----
    load_plane(zb - 2);
    load_plane(zb - 1);
    load_plane(zb);
    __syncthreads();
    s1_plane(zb - 1);
    __syncthreads();
    load_plane(zb + 1);
    __syncthreads();
    s1_plane(zb);
    __syncthreads();

    // ---- main loop: 16 owned z-planes ----
    double part = 0.0;
    for (int L = zb + 2; L < zb + 18; ++L) {
        load_plane(L);
        __syncthreads();
        s1_plane(L - 1);
        __syncthreads();

        int zo = L - 2;
        const float4* szm = ls1 + SLOT(zo - 1) * S1_P4;
        const float4* szc = ls1 + SLOT(zo)     * S1_P4;
        const float4* szp = ls1 + SLOT(zo + 1) * S1_P4;
        float4 c4 = szc[cix];
        float4 l4 = szc[cix - 1];
        float4 r4 = szc[cix + 1];
        float4 u4 = szc[cix - PITCH4];
        float4 d4 = szc[cix + PITCH4];
        float4 m4 = szm[cix];
        float4 p4 = szp[cix];
        float4 v;
        v.x = fmaxf((c4.x + l4.w + c4.y + u4.x + d4.x + m4.x + p4.x) * wk + bs, 0.f);
        v.y = fmaxf((c4.y + c4.x + c4.z + u4.y + d4.y + m4.y + p4.y) * wk + bs, 0.f);
        v.z = fmaxf((c4.z + c4.y + c4.w + u4.z + d4.z + m4.z + p4.z) * wk + bs, 0.f);
        v.w = fmaxf((c4.w + c4.z + r4.x + u4.w + d4.w + m4.w + p4.w) * wk + bs, 0.f);
        if (store) dp[(size_t)zo * 4096 + go4] = v;
        part += (double)c1 * ((double)c4.x + (double)c4.y + (double)c4.z + (double)c4.w)
              + (double)c2 * ((double)v.x  + (double)v.y  + (double)v.z  + (double)v.w);
    }

    // ---- block reduction, one f64 atomic per block ----
    #pragma unroll
    for (int off = 32; off > 0; off >>= 1)
        part += __shfl_down(part, off, 64);
    if ((tid & 63) == 0) wsum[tid >> 6] = part;
    __syncthreads();
    if (tid == 0) {
        double tot = wsum[0] + wsum[1] + wsum[2] + wsum[3];
        atomicAdd(&accs[bid & (NACC - 1)], tot * (double)weight[bc]);
    }
}

// Reduce the NACC spread accumulators -> scalar mean.
__global__ __launch_bounds__(1024) void finalize_kernel(
    const double* __restrict__ accs, float* __restrict__ out)
{
    __shared__ double wsum[16];
    double v = accs[threadIdx.x];
    #pragma unroll
    for (int off = 32; off > 0; off >>= 1)
        v += __shfl_down(v, off, 64);
    int lane = threadIdx.x & 63;
    int wid  = threadIdx.x >> 6;
    if (lane == 0) wsum[wid] = v;
    __syncthreads();
    if (threadIdx.x == 0) {
        double tot = 0.0;
        #pragma unroll
        for (int i = 0; i < 16; ++i) tot += wsum[i];
        out[0] = (float)(tot / (double)NTOT);
    }
}

extern "C" void kernel_launch(void* const* d_in, const int* in_sizes, int n_in,
                              void* d_out, int out_size, void* d_ws, size_t ws_size,
                              hipStream_t stream) {
    const float* in     = (const float*)d_in[0];
    const int*   tgt    = (const int*)d_in[1];
    const float* weight = (const float*)d_in[2];
    const float* kern   = (const float*)d_in[3];
    const float* bias   = (const float*)d_in[4];
    float* out = (float*)d_out;

    char* ws = (char*)d_ws;
    float*  buf0 = (float*)ws;
    float*  buf1 = (float*)(ws + (size_t)NTOT * sizeof(float));
    double* accs = (double*)(ws + (size_t)NTOT * 2 * sizeof(float));

    // 1) softmax + one-hot + square (also zeroes accs)
    softmax_sq_kernel<<<(NSITE / 4) / 256, 256, 0, stream>>>(in, tgt, buf0, accs);

    // 2) 5 fused double-erosion passes; last pass skips the store
    float* cur = buf0;
    float* nxt = buf1;
    for (int p = 0; p < 5; ++p) {
        float c1 = (float)((2 * p + 1) * (2 * p + 1));
        float c2 = (float)((2 * p + 2) * (2 * p + 2));
        int   store = (p < 4) ? 1 : 0;
        erode2_kernel<<<1024, 256, 0, stream>>>(
            (const float4*)cur, (float4*)nxt, kern, bias, weight, c1, c2, store, accs);
        float* t = cur; cur = nxt; nxt = t;
    }

    // 3) reduce + mean
    finalize_kernel<<<1, 1024, 0, stream>>>(accs, out);
}

// Round 6
// 270.772 us; speedup vs baseline: 2.8640x; 1.1674x over previous
//
#include <hip/hip_runtime.h>

// Problem constants (match reference)
#define DHW   (128*128*128)        // 2^21
#define CDHW  (4*DHW)              // 2^23
#define NTOT  (2*CDHW)             // 2^24 = 16,777,216
#define NSITE (2*DHW)              // B*DHW = 2^22 sites
#define NACC  1024                 // spread accumulator slots

// erode2 tiling: full x-row (32 f4), 8 owned y-rows, 16 owned z-planes.
#define ROW4    32
#define IN_ROWS 12                 // 8 + 2*2 y-halo
#define S1_ROWS 10                 // 8 + 2*1
#define IN_P4   (IN_ROWS*ROW4)     // 384 f4 / input plane
#define S1_P4   (S1_ROWS*ROW4)     // 320 f4 / s1 plane
#define SLOT(z) (((z)+6)%3)

// Kernel A: softmax over C=4, subtract one-hot(target), square -> buf0.
// 2 float4 site-groups per thread for memory-level parallelism. Zeros accs.
__global__ __launch_bounds__(256) void softmax_sq_kernel(
    const float* __restrict__ in, const int* __restrict__ tgt,
    float* __restrict__ out, double* __restrict__ accs)
{
    int tid = threadIdx.x;
    int gid = blockIdx.x * 256 + tid;
    if (gid < NACC) accs[gid] = 0.0;

    #pragma unroll
    for (int half = 0; half < 2; ++half) {
        int j4 = blockIdx.x * 512 + half * 256 + tid;  // [0, NSITE/4)
        int base = j4 << 2;
        int b = base >> 21;
        int s = base & (DHW - 1);
        const float* p = in + (size_t)b * CDHW + s;

        float4 a0 = *(const float4*)(p);
        float4 a1 = *(const float4*)(p + DHW);
        float4 a2 = *(const float4*)(p + 2 * DHW);
        float4 a3 = *(const float4*)(p + 3 * DHW);
        int4   t  = *(const int4*)(tgt + base);

        float4 o0, o1, o2, o3;
        #define SOFTMAX1(K)                                                    \
        {                                                                      \
            float v0 = a0.K, v1 = a1.K, v2 = a2.K, v3 = a3.K;                  \
            float m  = fmaxf(fmaxf(v0, v1), fmaxf(v2, v3));                    \
            float e0 = expf(v0 - m), e1 = expf(v1 - m);                        \
            float e2 = expf(v2 - m), e3 = expf(v3 - m);                        \
            float inv = 1.0f / (e0 + e1 + e2 + e3);                            \
            int   tv = t.K;                                                    \
            float d0 = e0 * inv - (tv == 0 ? 1.0f : 0.0f);                     \
            float d1 = e1 * inv - (tv == 1 ? 1.0f : 0.0f);                     \
            float d2 = e2 * inv - (tv == 2 ? 1.0f : 0.0f);                     \
            float d3 = e3 * inv - (tv == 3 ? 1.0f : 0.0f);                     \
            o0.K = d0 * d0; o1.K = d1 * d1; o2.K = d2 * d2; o3.K = d3 * d3;    \
        }
        SOFTMAX1(x) SOFTMAX1(y) SOFTMAX1(z) SOFTMAX1(w)
        #undef SOFTMAX1

        float* q = out + (size_t)b * CDHW + s;
        *(float4*)(q)           = o0;
        *(float4*)(q + DHW)     = o1;
        *(float4*)(q + 2 * DHW) = o2;
        *(float4*)(q + 3 * DHW) = o3;
    }
}

// Kernel B: TWO fused erosion steps; full-row tiles, z-marching rolling
// planes, register-prefetch of the next z-plane (load latency hidden by one
// full iteration). All LDS ops lane-consecutive float4.
__global__ __launch_bounds__(256, 4) void erode2_kernel(
    const float4* __restrict__ src, float4* __restrict__ dst,
    const float* __restrict__ kern, const float* __restrict__ bias,
    const float* __restrict__ weight, float c1, float c2,
    int store, double* __restrict__ accs)
{
    __shared__ float4 lin[3 * IN_P4];   // 18.4 KB
    __shared__ float4 ls1[3 * S1_P4];   // 15.4 KB
    __shared__ double wsum[4];

    const int tid = threadIdx.x;
    const int bid = blockIdx.x;
    const int yt = bid & 15;
    const int zs = (bid >> 4) & 7;
    const int bc = bid >> 7;            // b*4 + c in [0,8)
    const int y0 = yt << 3;
    const int zb = zs << 4;

    const float4* sp = src + ((size_t)bc << 19);   // slab = 2^19 f4
    float4*       dp = dst + ((size_t)bc << 19);
    const float wk = kern[13];          // all 7 taps equal
    const float bs = bias[bc & 3];

    const int col  = tid & 31;
    const int trow = tid >> 5;

    // ---- load maps (input rows 0..11 <-> gy = y0+row-2) ----
    const int  gy0  = y0 + trow - 2;
    const bool lv0  = ((unsigned)gy0 < 128u);
    const int  off0 = (lv0 ? gy0 : 0) * 32 + col;
    const bool act1 = (tid < 128);                 // rows 8..11
    const int  gy1  = y0 + trow + 6;
    const bool lv1  = act1 && ((unsigned)gy1 < 128u);
    const int  off1 = (lv1 ? gy1 : 0) * 32 + col;

    // ---- s1 maps (s1 rows 0..9 <-> gy = y0+r-1) ----
    const float m0  = ((unsigned)(y0 + trow - 1) < 128u) ? 1.f : 0.f;
    const int   ci0 = (trow + 1) * 32 + col;
    const bool  sact1 = (tid < 64);                // s1 rows 8..9
    const int   r1  = 8 + trow;
    const float m1  = ((unsigned)(y0 + r1 - 1) < 128u) ? 1.f : 0.f;
    const int   ci1 = (r1 + 1) * 32 + col;

    const float lmask = (col == 0)  ? 0.f : 1.f;   // x=0 edge
    const float rmask = (col == 31) ? 0.f : 1.f;   // x=127 edge

    // ---- step2 map (owned oy = trow 0..7) ----
    const int cix = (trow + 1) * 32 + col;
    const int go4 = (y0 + trow) * 32 + col;

    const float4 f4z = make_float4(0.f, 0.f, 0.f, 0.f);
    float4 pf0 = f4z, pf1 = f4z;

    auto prefetch = [&](int L) {
        pf0 = f4z; pf1 = f4z;
        if ((unsigned)L < 128u) {
            const float4* zp = sp + ((size_t)L << 12);
            if (lv0) pf0 = zp[off0];
            if (lv1) pf1 = zp[off1];
        }
    };
    auto commit = [&](int L) {
        float4* sl = lin + SLOT(L) * IN_P4;
        sl[tid] = pf0;
        if (act1) sl[256 + tid] = pf1;
    };
    auto s1one = [&](const float4* pzm, const float4* pzc, const float4* pzp,
                     int ci, float ym) -> float4 {
        float4 qC = pzc[ci];
        float4 qL = pzc[ci - 1];
        float4 qR = pzc[ci + 1];
        float4 qU = pzc[ci - 32];
        float4 qD = pzc[ci + 32];
        float4 qm = pzm[ci];
        float4 qp = pzp[ci];
        float lf = qL.w * lmask;
        float rt = qR.x * rmask;
        float4 v;
        v.x = fmaxf((qC.x + lf   + qC.y + qU.x + qD.x + qm.x + qp.x) * wk + bs, 0.f) * ym;
        v.y = fmaxf((qC.y + qC.x + qC.z + qU.y + qD.y + qm.y + qp.y) * wk + bs, 0.f) * ym;
        v.z = fmaxf((qC.z + qC.y + qC.w + qU.z + qD.z + qm.z + qp.z) * wk + bs, 0.f) * ym;
        v.w = fmaxf((qC.w + qC.z + rt   + qU.w + qD.w + qm.w + qp.w) * wk + bs, 0.f) * ym;
        return v;
    };
    auto s1_plane = [&](int z) {
        float4* o = ls1 + SLOT(z) * S1_P4;
        if ((unsigned)z < 128u) {
            const float4* pzm = lin + SLOT(z - 1) * IN_P4;
            const float4* pzc = lin + SLOT(z)     * IN_P4;
            const float4* pzp = lin + SLOT(z + 1) * IN_P4;
            o[tid] = s1one(pzm, pzc, pzp, ci0, m0);
            if (sact1) o[256 + tid] = s1one(pzm, pzc, pzp, ci1, m1);
        } else {
            o[tid] = f4z;
            if (sact1) o[256 + tid] = f4z;
        }
    };

    double part = 0.0;

    // ---- prologue ----
    prefetch(zb - 2); commit(zb - 2);
    prefetch(zb - 1); commit(zb - 1);
    prefetch(zb);     commit(zb);
    prefetch(zb + 1);                       // stays in regs
    __syncthreads();
    s1_plane(zb - 1);
    __syncthreads();

    // ---- main loop: L = plane committed this iter ----
    for (int L = zb + 1; L <= zb + 17; ++L) {
        commit(L);                          // regs from last iter's prefetch
        if (L <= zb + 16) prefetch(L + 1);  // issue next load, no wait
        __syncthreads();
        s1_plane(L - 1);                    // reads lin L-2..L
        __syncthreads();
        int zo = L - 2;                     // s1 ring holds L-3..L-1
        if (zo >= zb) {
            const float4* szm = ls1 + SLOT(zo - 1) * S1_P4;
            const float4* szc = ls1 + SLOT(zo)     * S1_P4;
            const float4* szp = ls1 + SLOT(zo + 1) * S1_P4;
            float4 c4 = szc[cix];
            float4 l4 = szc[cix - 1];
            float4 r4 = szc[cix + 1];
            float4 u4 = szc[cix - 32];
            float4 d4 = szc[cix + 32];
            float4 m4 = szm[cix];
            float4 p4 = szp[cix];
            float lf = l4.w * lmask;
            float rt = r4.x * rmask;
            float4 v;
            v.x = fmaxf((c4.x + lf   + c4.y + u4.x + d4.x + m4.x + p4.x) * wk + bs, 0.f);
            v.y = fmaxf((c4.y + c4.x + c4.z + u4.y + d4.y + m4.y + p4.y) * wk + bs, 0.f);
            v.z = fmaxf((c4.z + c4.y + c4.w + u4.z + d4.z + m4.z + p4.z) * wk + bs, 0.f);
            v.w = fmaxf((c4.w + c4.z + rt   + u4.w + d4.w + m4.w + p4.w) * wk + bs, 0.f);
            if (store) dp[((size_t)zo << 12) + go4] = v;
            part += (double)c1 * ((double)c4.x + (double)c4.y + (double)c4.z + (double)c4.w)
                  + (double)c2 * ((double)v.x  + (double)v.y  + (double)v.z  + (double)v.w);
        }
    }

    // ---- block reduction, one f64 atomic per block ----
    #pragma unroll
    for (int off = 32; off > 0; off >>= 1)
        part += __shfl_down(part, off, 64);
    if ((tid & 63) == 0) wsum[tid >> 6] = part;
    __syncthreads();
    if (tid == 0) {
        double tot = wsum[0] + wsum[1] + wsum[2] + wsum[3];
        atomicAdd(&accs[bid & (NACC - 1)], tot * (double)weight[bc]);
    }
}

// Reduce the NACC spread accumulators -> scalar mean.
__global__ __launch_bounds__(1024) void finalize_kernel(
    const double* __restrict__ accs, float* __restrict__ out)
{
    __shared__ double wsum[16];
    double v = accs[threadIdx.x];
    #pragma unroll
    for (int off = 32; off > 0; off >>= 1)
        v += __shfl_down(v, off, 64);
    int lane = threadIdx.x & 63;
    int wid  = threadIdx.x >> 6;
    if (lane == 0) wsum[wid] = v;
    __syncthreads();
    if (threadIdx.x == 0) {
        double tot = 0.0;
        #pragma unroll
        for (int i = 0; i < 16; ++i) tot += wsum[i];
        out[0] = (float)(tot / (double)NTOT);
    }
}

extern "C" void kernel_launch(void* const* d_in, const int* in_sizes, int n_in,
                              void* d_out, int out_size, void* d_ws, size_t ws_size,
                              hipStream_t stream) {
    const float* in     = (const float*)d_in[0];
    const int*   tgt    = (const int*)d_in[1];
    const float* weight = (const float*)d_in[2];
    const float* kern   = (const float*)d_in[3];
    const float* bias   = (const float*)d_in[4];
    float* out = (float*)d_out;

    char* ws = (char*)d_ws;
    float*  buf0 = (float*)ws;
    float*  buf1 = (float*)(ws + (size_t)NTOT * sizeof(float));
    double* accs = (double*)(ws + (size_t)NTOT * 2 * sizeof(float));

    // 1) softmax + one-hot + square (also zeroes accs); 2 f4 per thread
    softmax_sq_kernel<<<(NSITE / 8) / 256, 256, 0, stream>>>(in, tgt, buf0, accs);

    // 2) 5 fused double-erosion passes; last pass skips the store
    float* cur = buf0;
    float* nxt = buf1;
    for (int p = 0; p < 5; ++p) {
        float c1 = (float)((2 * p + 1) * (2 * p + 1));
        float c2 = (float)((2 * p + 2) * (2 * p + 2));
        int   store = (p < 4) ? 1 : 0;
        erode2_kernel<<<1024, 256, 0, stream>>>(
            (const float4*)cur, (float4*)nxt, kern, bias, weight, c1, c2, store, accs);
        float* t = cur; cur = nxt; nxt = t;
    }

    // 3) reduce + mean
    finalize_kernel<<<1, 1024, 0, stream>>>(accs, out);
}